// Round 2
// baseline (883.463 us; speedup 1.0000x reference)
//
#include <hip/hip_runtime.h>
#include <math.h>

// ---------------------------------------------------------------------------
// CrossAttention via bf16-split-3 MFMA GEMMs (fp32-class accuracy).
//   B=8, LQ=LKV=1024, EQ=1024, EKV=768, H=8, HD=128
//   d_out = [ out (8*1024*1024) | attn (64*1024*1024) ] fp32
//
// Every GEMM: A [M][K] row-major, B [N][K] row-major, C [M][N] fp32.
// fp32 operands are split on the fly into hi/lo bf16 (x ~= hi + lo), and
// A.B is computed as Ahi.Bhi + Ahi.Blo + Alo.Bhi via mfma_f32_16x16x32_bf16
// (3 MFMAs; dropped lo.lo term ~2^-16 relative => ~1e-5 accuracy).
//
// Pipeline:
//   0) transpose w_q/w_k/w_v per head -> wT* [h][128][E]   (B needs [N][K])
//   1) Q = query @ w_q  -> bufQ  [h][b][l][d]
//   2) K = key   @ w_k  -> bufK  [h][b][l][d]
//   3) V = value @ w_v  -> bufVT [h][b][d][l]   (transposed epilogue)
//   4) S = Q K^T / sqrt(128) -> attn region [h][b][lq][lkv]
//   5) row softmax in place
//   6) O = attn @ V -> bufO (=bufQ reused) in concat layout [b][l][h*128+d]
//   7) out = O @ proj_w^T + proj_b
// Workspace: 3*32MB big buffers + 10MB transposed weights ~= 111 MB.
// ---------------------------------------------------------------------------

using bf16x8 = __attribute__((ext_vector_type(8))) short;  // 8 bf16 (4 VGPR)
using f32x4  = __attribute__((ext_vector_type(4))) float;  // MFMA acc

__device__ __forceinline__ unsigned bf16_rne(float x) {
    unsigned u = __float_as_uint(x);
    return (u + 0x7fffu + ((u >> 16) & 1u)) >> 16;
}

// ---------------------------------------------------------------------------
// 32x32 tiled transpose: src [R][C] -> dst [C][R], blockIdx.z = head.
__global__ __launch_bounds__(256) void transpose_k(
    const float* __restrict__ src, float* __restrict__ dst, int R, int C)
{
    __shared__ float tile[32][33];
    const long off = (long)blockIdx.z * R * C;
    src += off; dst += off;
    const int r0 = blockIdx.y * 32, c0 = blockIdx.x * 32;
    const int tx = threadIdx.x & 31, ty = threadIdx.x >> 5;  // 32 x 8
    #pragma unroll
    for (int i = 0; i < 4; ++i)
        tile[ty + i * 8][tx] = src[(long)(r0 + ty + i * 8) * C + c0 + tx];
    __syncthreads();
    #pragma unroll
    for (int i = 0; i < 4; ++i)
        dst[(long)(c0 + ty + i * 8) * R + r0 + tx] = tile[tx][ty + i * 8];
}

// ---------------------------------------------------------------------------
// Split-3 bf16 MFMA GEMM. Tile 128x128, BK=32, 256 threads = 4 waves (2x2),
// each wave computes 64x64 via 4x4 fragments of 16x16x32.
//   batch: z -> h = z>>3, b = z&7; X += h*HS + b*BS.
//   VT=1: write C transposed (C[col*ldc + row], used for V^T).
template <bool VT, bool BIAS>
__global__ __launch_bounds__(256, 2) void gemm3(
    const float* __restrict__ A, int lda, long aHS, long aBS,
    const float* __restrict__ Bm, int ldb, long bHS, long bBS,
    float* __restrict__ C, int ldc, long cHS, long cBS,
    int K, float scale, const float* __restrict__ bias)
{
    const int z = blockIdx.z, hh = z >> 3, bb = z & 7;
    A  += (long)hh * aHS + (long)bb * aBS;
    Bm += (long)hh * bHS + (long)bb * bBS;
    C  += (long)hh * cHS + (long)bb * cBS;

    __shared__ short Ahi[128 * 32];
    __shared__ short Alo[128 * 32];
    __shared__ short Bhi[128 * 32];
    __shared__ short Blo[128 * 32];

    const int t    = threadIdx.x;
    const int lane = t & 63, wid = t >> 6;
    const int wr = wid >> 1, wc = wid & 1;     // wave 2x2 over the 128x128 tile
    const int fr = lane & 15, fg = lane >> 4;  // fragment row/col, k-group

    const int m0 = blockIdx.y * 128, n0 = blockIdx.x * 128;

    // staging: thread -> (row, k-half): 128 rows x 2 halves of 16 floats
    const int srow = t >> 1;
    const int skh  = (t & 1) << 4;
    const int sb   = srow * 32 + skh;

    f32x4 acc[4][4] = {};

    for (int k0 = 0; k0 < K; k0 += 32) {
        // ---- stage A tile (128 x 32) ----
        {
            const float* g = A + (long)(m0 + srow) * lda + (k0 + skh);
            const float4 f0 = *(const float4*)(g);
            const float4 f1 = *(const float4*)(g + 4);
            const float4 f2 = *(const float4*)(g + 8);
            const float4 f3 = *(const float4*)(g + 12);
            const float fv[16] = {f0.x, f0.y, f0.z, f0.w, f1.x, f1.y, f1.z, f1.w,
                                  f2.x, f2.y, f2.z, f2.w, f3.x, f3.y, f3.z, f3.w};
            bf16x8 h0, l0, h1, l1;
            #pragma unroll
            for (int i = 0; i < 8; ++i) {
                unsigned ha = bf16_rne(fv[i]);
                h0[i] = (short)ha;
                l0[i] = (short)bf16_rne(fv[i] - __uint_as_float(ha << 16));
                unsigned hb = bf16_rne(fv[8 + i]);
                h1[i] = (short)hb;
                l1[i] = (short)bf16_rne(fv[8 + i] - __uint_as_float(hb << 16));
            }
            *(bf16x8*)&Ahi[sb] = h0;  *(bf16x8*)&Ahi[sb + 8] = h1;
            *(bf16x8*)&Alo[sb] = l0;  *(bf16x8*)&Alo[sb + 8] = l1;
        }
        // ---- stage B tile (128 x 32) ----
        {
            const float* g = Bm + (long)(n0 + srow) * ldb + (k0 + skh);
            const float4 f0 = *(const float4*)(g);
            const float4 f1 = *(const float4*)(g + 4);
            const float4 f2 = *(const float4*)(g + 8);
            const float4 f3 = *(const float4*)(g + 12);
            const float fv[16] = {f0.x, f0.y, f0.z, f0.w, f1.x, f1.y, f1.z, f1.w,
                                  f2.x, f2.y, f2.z, f2.w, f3.x, f3.y, f3.z, f3.w};
            bf16x8 h0, l0, h1, l1;
            #pragma unroll
            for (int i = 0; i < 8; ++i) {
                unsigned ha = bf16_rne(fv[i]);
                h0[i] = (short)ha;
                l0[i] = (short)bf16_rne(fv[i] - __uint_as_float(ha << 16));
                unsigned hb = bf16_rne(fv[8 + i]);
                h1[i] = (short)hb;
                l1[i] = (short)bf16_rne(fv[8 + i] - __uint_as_float(hb << 16));
            }
            *(bf16x8*)&Bhi[sb] = h0;  *(bf16x8*)&Bhi[sb + 8] = h1;
            *(bf16x8*)&Blo[sb] = l0;  *(bf16x8*)&Blo[sb + 8] = l1;
        }
        __syncthreads();

        // ---- fragments + MFMA ----
        bf16x8 ah[4], al[4];
        #pragma unroll
        for (int m = 0; m < 4; ++m) {
            const int r = (wr * 64 + m * 16 + fr) * 32 + fg * 8;
            ah[m] = *(const bf16x8*)&Ahi[r];
            al[m] = *(const bf16x8*)&Alo[r];
        }
        #pragma unroll
        for (int n = 0; n < 4; ++n) {
            const int r = (wc * 64 + n * 16 + fr) * 32 + fg * 8;
            const bf16x8 bh = *(const bf16x8*)&Bhi[r];
            const bf16x8 bl = *(const bf16x8*)&Blo[r];
            #pragma unroll
            for (int m = 0; m < 4; ++m) {
                acc[m][n] = __builtin_amdgcn_mfma_f32_16x16x32_bf16(ah[m], bh, acc[m][n], 0, 0, 0);
                acc[m][n] = __builtin_amdgcn_mfma_f32_16x16x32_bf16(ah[m], bl, acc[m][n], 0, 0, 0);
                acc[m][n] = __builtin_amdgcn_mfma_f32_16x16x32_bf16(al[m], bh, acc[m][n], 0, 0, 0);
            }
        }
        __syncthreads();
    }

    // ---- epilogue: C/D layout col=lane&15, row=(lane>>4)*4+reg ----
    #pragma unroll
    for (int m = 0; m < 4; ++m) {
        const int row0 = m0 + wr * 64 + m * 16 + fg * 4;
        #pragma unroll
        for (int n = 0; n < 4; ++n) {
            const int col = n0 + wc * 64 + n * 16 + fr;
            const f32x4 v = acc[m][n];
            if (VT) {
                float4 w4;
                w4.x = v[0] * scale; w4.y = v[1] * scale;
                w4.z = v[2] * scale; w4.w = v[3] * scale;
                *(float4*)&C[(long)col * ldc + row0] = w4;  // 4 rows contiguous
            } else {
                const float bv = BIAS ? bias[col] : 0.0f;
                #pragma unroll
                for (int i = 0; i < 4; ++i)
                    C[(long)(row0 + i) * ldc + col] = v[i] * scale + bv;
            }
        }
    }
}

// ---------------------------------------------------------------------------
// In-place softmax over rows of 1024. One 256-thread block per row.
__global__ __launch_bounds__(256) void softmax_rows(float* __restrict__ attn)
{
    const long row = blockIdx.x;
    float* p = attn + row * 1024 + (long)threadIdx.x * 4;
    float4 v = *reinterpret_cast<float4*>(p);

    float m = fmaxf(fmaxf(v.x, v.y), fmaxf(v.z, v.w));
    #pragma unroll
    for (int off = 32; off > 0; off >>= 1)
        m = fmaxf(m, __shfl_down(m, off));

    __shared__ float red[4];
    const int wave = threadIdx.x >> 6, lane = threadIdx.x & 63;
    if (lane == 0) red[wave] = m;
    __syncthreads();
    m = fmaxf(fmaxf(red[0], red[1]), fmaxf(red[2], red[3]));
    __syncthreads();

    v.x = __expf(v.x - m); v.y = __expf(v.y - m);
    v.z = __expf(v.z - m); v.w = __expf(v.w - m);
    float s = v.x + v.y + v.z + v.w;
    #pragma unroll
    for (int off = 32; off > 0; off >>= 1)
        s += __shfl_down(s, off);
    if (lane == 0) red[wave] = s;
    __syncthreads();
    s = red[0] + red[1] + red[2] + red[3];

    const float r = 1.0f / s;
    v.x *= r; v.y *= r; v.z *= r; v.w *= r;
    *reinterpret_cast<float4*>(p) = v;
}

// ---------------------------------------------------------------------------
extern "C" void kernel_launch(void* const* d_in, const int* in_sizes, int n_in,
                              void* d_out, int out_size, void* d_ws, size_t ws_size,
                              hipStream_t stream)
{
    const float* query  = (const float*)d_in[0];  // (8,1024,1024)
    const float* key    = (const float*)d_in[1];  // (8,1024,768)
    const float* value  = (const float*)d_in[2];  // (8,1024,768)
    const float* w_q    = (const float*)d_in[3];  // (8,1024,128)
    const float* w_k    = (const float*)d_in[4];  // (8,768,128)
    const float* w_v    = (const float*)d_in[5];  // (8,768,128)
    const float* proj_w = (const float*)d_in[6];  // (1024,1024)
    const float* proj_b = (const float*)d_in[7];  // (1024,)

    float* out  = (float*)d_out;
    float* attn = out + (size_t)8 * 1024 * 1024;       // [h][b][1024][1024]

    const size_t SZ = (size_t)8 * 1024 * 1024;         // 8,388,608 floats
    float* bufQ  = (float*)d_ws;                       // [h][b][l][d]
    float* bufK  = bufQ + SZ;                          // [h][b][l][d]
    float* bufVT = bufK + SZ;                          // [h][b][d][l]
    float* wTq   = bufVT + SZ;                         // [h][128][1024]
    float* wTk   = wTq + (size_t)8 * 128 * 1024;       // [h][128][768]
    float* wTv   = wTk + (size_t)8 * 128 * 768;        // [h][128][768]
    float* bufO  = bufQ;                               // reuse after QK^T

    const dim3 blk(256);
    const float isq = 0.08838834764831845f;            // 1/sqrt(128)

    // 0) weight transposes: [E][128] -> [128][E] per head
    transpose_k<<<dim3(4, 32, 8), blk, 0, stream>>>(w_q, wTq, 1024, 128);
    transpose_k<<<dim3(4, 24, 8), blk, 0, stream>>>(w_k, wTk, 768, 128);
    transpose_k<<<dim3(4, 24, 8), blk, 0, stream>>>(w_v, wTv, 768, 128);

    // 1) Q projection: per (h,b) [1024x1024] x [128x1024]^T
    gemm3<false, false><<<dim3(1, 8, 64), blk, 0, stream>>>(
        query, 1024, 0L, 1048576L,
        wTq,   1024, 131072L, 0L,
        bufQ,  128,  1048576L, 131072L,
        1024, 1.0f, nullptr);

    // 2) K projection (K=768)
    gemm3<false, false><<<dim3(1, 8, 64), blk, 0, stream>>>(
        key,  768, 0L, (long)1024 * 768,
        wTk,  768, (long)128 * 768, 0L,
        bufK, 128, 1048576L, 131072L,
        768, 1.0f, nullptr);

    // 3) V projection -> V^T layout
    gemm3<true, false><<<dim3(1, 8, 64), blk, 0, stream>>>(
        value, 768, 0L, (long)1024 * 768,
        wTv,   768, (long)128 * 768, 0L,
        bufVT, 1024, 1048576L, 131072L,
        768, 1.0f, nullptr);

    // 4) scores: per (h,b) Q [1024x128] x K [1024x128]^T -> attn
    gemm3<false, false><<<dim3(8, 8, 64), blk, 0, stream>>>(
        bufQ, 128, 1048576L, 131072L,
        bufK, 128, 1048576L, 131072L,
        attn, 1024, (long)8 * 1048576, 1048576L,
        128, isq, nullptr);

    // 5) softmax rows in place
    softmax_rows<<<65536, blk, 0, stream>>>(attn);

    // 6) O = attn @ V -> concat layout [b][l][h*128+d]
    gemm3<false, false><<<dim3(1, 8, 64), blk, 0, stream>>>(
        attn,  1024, (long)8 * 1048576, 1048576L,
        bufVT, 1024, 1048576L, 131072L,
        bufO,  1024, 128L, 1048576L,
        1024, 1.0f, nullptr);

    // 7) out = O @ proj_w^T + proj_b
    gemm3<false, true><<<dim3(8, 64, 1), blk, 0, stream>>>(
        bufO,   1024, 0L, 0L,
        proj_w, 1024, 0L, 0L,
        out,    1024, 0L, 0L,
        1024, 1.0f, proj_b);
}

// Round 5
// 835.959 us; speedup vs baseline: 1.0568x; 1.0568x over previous
//
#include <hip/hip_runtime.h>
#include <math.h>

// ---------------------------------------------------------------------------
// CrossAttention via pre-split bf16-pair MFMA GEMMs (fp32-class accuracy).
//   B=8, LQ=LKV=1024, EQ=1024, EKV=768, H=8, HD=128
//   d_out = [ out (8*1024*1024) | attn (64*1024*1024) ] fp32
//
// All values x are carried as bf16 pairs (hi, lo) with x ~= hi + lo;
// A.B = Ahi.Bhi + Ahi.Blo + Alo.Bhi  (3x mfma_f32_16x16x32_bf16).
// Splitting is hoisted out of the GEMMs: operands are pre-split in global
// memory, so GEMM staging is pure global_load_lds (16B) -> LDS -> MFMA.
// Identical numerics to the round-2 kernel (same hi/lo, same dropped term).
//
// Buffers:
//   ws (100 MB):  Qhi/Qlo, Khi/Klo, VThi/VTlo, pwh/pwl; O reuses Q region.
//   d_out attn region (scratch until QK^T): wT* splits, query/key/value splits.
// ---------------------------------------------------------------------------

using bf16x8 = __attribute__((ext_vector_type(8))) short;
using f32x4  = __attribute__((ext_vector_type(4))) float;

__device__ __forceinline__ unsigned bf16_rne(float x) {
    unsigned u = __float_as_uint(x);
    return (u + 0x7fffu + ((u >> 16) & 1u)) >> 16;
}

#define AS1 __attribute__((address_space(1)))
#define AS3 __attribute__((address_space(3)))

// 16B direct global->LDS. LDS dest: wave-uniform base + lane*16 (implicit).
__device__ __forceinline__ void gl_lds16(const short* g, short* l) {
    __builtin_amdgcn_global_load_lds((AS1 unsigned*)g, (AS3 unsigned*)l, 16, 0, 0);
}

// ---------------------------------------------------------------------------
// Split fp32 -> (hi, lo) bf16 pair. 8 elems/thread, exact-sized grid.
__global__ __launch_bounds__(256) void split_f32(
    const float* __restrict__ src, short* __restrict__ hi,
    short* __restrict__ lo)
{
    const long i = ((long)blockIdx.x * 256 + threadIdx.x) * 8;
    const float4 a = *(const float4*)(src + i);
    const float4 b = *(const float4*)(src + i + 4);
    const float fv[8] = {a.x, a.y, a.z, a.w, b.x, b.y, b.z, b.w};
    bf16x8 h, l;
    #pragma unroll
    for (int j = 0; j < 8; ++j) {
        unsigned hb = bf16_rne(fv[j]);
        h[j] = (short)hb;
        l[j] = (short)bf16_rne(fv[j] - __uint_as_float(hb << 16));
    }
    *(bf16x8*)(hi + i) = h;
    *(bf16x8*)(lo + i) = l;
}

// ---------------------------------------------------------------------------
// Transpose + split: src [R][C] fp32 -> dhi/dlo [C][R] bf16. z = head.
__global__ __launch_bounds__(256) void transpose_split(
    const float* __restrict__ src, short* __restrict__ dhi,
    short* __restrict__ dlo, int R, int C)
{
    __shared__ float tile[32][33];
    src += (long)blockIdx.z * R * C;
    dhi += (long)blockIdx.z * R * C;
    dlo += (long)blockIdx.z * R * C;
    const int r0 = blockIdx.y * 32, c0 = blockIdx.x * 32;
    const int tx = threadIdx.x & 31, ty = threadIdx.x >> 5;  // 32 x 8
    #pragma unroll
    for (int i = 0; i < 4; ++i)
        tile[ty + i * 8][tx] = src[(long)(r0 + ty + i * 8) * C + c0 + tx];
    __syncthreads();
    #pragma unroll
    for (int i = 0; i < 4; ++i) {
        const float v = tile[tx][ty + i * 8];
        const unsigned h = bf16_rne(v);
        const long o = (long)(c0 + ty + i * 8) * R + r0 + tx;
        dhi[o] = (short)h;
        dlo[o] = (short)bf16_rne(v - __uint_as_float(h << 16));
    }
}

// ---------------------------------------------------------------------------
// Split-3 bf16-pair GEMM. C = (A0+A1).(B0+B1)^T (lo.lo dropped), tile
// 128x128, BK=32, 256 thr = 4 waves (2x2), 4x4 16x16x32 frags per wave.
//   AF32=1: A0 is fp32, split on the fly (used for PV where A=attn).
//   EP: 0 = fp32 C (scale, opt bias), 1 = split C (hi/lo), 2 = split C^T.
//   batch: z -> hh = z>>3, bb = z&7.
template <bool AF32, int EP, bool BIAS>
__global__ __launch_bounds__(256, 2) void gemm_bb(
    const void* __restrict__ A0, const void* __restrict__ A1, int lda, long aHS, long aBS,
    const short* __restrict__ B0, const short* __restrict__ B1, int ldb, long bHS, long bBS,
    void* __restrict__ C0, void* __restrict__ C1, int ldc, long cHS, long cBS,
    int K, float scale, const float* __restrict__ bias)
{
    const int z = blockIdx.z, hh = z >> 3, bb = z & 7;
    const long aoff = (long)hh * aHS + (long)bb * aBS;
    const long boff = (long)hh * bHS + (long)bb * bBS;
    const long coff = (long)hh * cHS + (long)bb * cBS;

    __shared__ short lAhi[4096];  // [128][32] linear (gl_lds requires linear)
    __shared__ short lAlo[4096];
    __shared__ short lBhi[4096];
    __shared__ short lBlo[4096];

    const int t    = threadIdx.x;
    const int lane = t & 63, wid = t >> 6;
    const int wr = wid >> 1, wc = wid & 1;
    const int fr = lane & 15, fg = lane >> 4;

    const int m0 = blockIdx.y * 128, n0 = blockIdx.x * 128;

    const short* Bh = B0 + boff;
    const short* Bl = B1 + boff;
    const short* Ah = AF32 ? nullptr : (const short*)A0 + aoff;
    const short* Al = AF32 ? nullptr : (const short*)A1 + aoff;
    const float* Af = AF32 ? (const float*)A0 + aoff : nullptr;

    // gl_lds mapping: issue (wid,j) covers rows wid*32+j*16 .. +15
    const int glrow = (lane >> 2);          // + wid*32 + j*16
    const int glk   = (lane & 3) * 8;
    // fp32 on-fly split mapping (AF32): thread -> (row, 16-float half)
    const int srow = t >> 1;
    const int shalf = (t & 1) * 16;

    f32x4 acc[4][4] = {};

    for (int k0 = 0; k0 < K; k0 += 32) {
        if (AF32) {
            const float* g = Af + (long)(m0 + srow) * lda + k0 + shalf;
            const float4 f0 = *(const float4*)(g);
            const float4 f1 = *(const float4*)(g + 4);
            const float4 f2 = *(const float4*)(g + 8);
            const float4 f3 = *(const float4*)(g + 12);
            const float fv[16] = {f0.x, f0.y, f0.z, f0.w, f1.x, f1.y, f1.z, f1.w,
                                  f2.x, f2.y, f2.z, f2.w, f3.x, f3.y, f3.z, f3.w};
            bf16x8 h0, l0, h1, l1;
            #pragma unroll
            for (int i = 0; i < 8; ++i) {
                unsigned ha = bf16_rne(fv[i]);
                h0[i] = (short)ha;
                l0[i] = (short)bf16_rne(fv[i] - __uint_as_float(ha << 16));
                unsigned hb = bf16_rne(fv[8 + i]);
                h1[i] = (short)hb;
                l1[i] = (short)bf16_rne(fv[8 + i] - __uint_as_float(hb << 16));
            }
            const int sb = srow * 32 + shalf;
            *(bf16x8*)&lAhi[sb] = h0;  *(bf16x8*)&lAhi[sb + 8] = h1;
            *(bf16x8*)&lAlo[sb] = l0;  *(bf16x8*)&lAlo[sb + 8] = l1;
        } else {
            #pragma unroll
            for (int j = 0; j < 2; ++j) {
                const int rowb = wid * 32 + j * 16 + glrow;
                const long go = (long)(m0 + rowb) * lda + k0 + glk;
                gl_lds16(Ah + go, &lAhi[(wid * 2 + j) * 512]);
                gl_lds16(Al + go, &lAlo[(wid * 2 + j) * 512]);
            }
        }
        #pragma unroll
        for (int j = 0; j < 2; ++j) {
            const int rowb = wid * 32 + j * 16 + glrow;
            const long go = (long)(n0 + rowb) * ldb + k0 + glk;
            gl_lds16(Bh + go, &lBhi[(wid * 2 + j) * 512]);
            gl_lds16(Bl + go, &lBlo[(wid * 2 + j) * 512]);
        }
        __syncthreads();

        bf16x8 va[4], wa[4];
        #pragma unroll
        for (int m = 0; m < 4; ++m) {
            const int off = (wr * 64 + m * 16 + fr) * 32 + fg * 8;
            va[m] = *(const bf16x8*)&lAhi[off];
            wa[m] = *(const bf16x8*)&lAlo[off];
        }
        #pragma unroll
        for (int n = 0; n < 4; ++n) {
            const int off = (wc * 64 + n * 16 + fr) * 32 + fg * 8;
            const bf16x8 vb = *(const bf16x8*)&lBhi[off];
            const bf16x8 wb = *(const bf16x8*)&lBlo[off];
            #pragma unroll
            for (int m = 0; m < 4; ++m) {
                acc[m][n] = __builtin_amdgcn_mfma_f32_16x16x32_bf16(va[m], vb, acc[m][n], 0, 0, 0);
                acc[m][n] = __builtin_amdgcn_mfma_f32_16x16x32_bf16(va[m], wb, acc[m][n], 0, 0, 0);
                acc[m][n] = __builtin_amdgcn_mfma_f32_16x16x32_bf16(wa[m], vb, acc[m][n], 0, 0, 0);
            }
        }
        __syncthreads();
    }

    // epilogue: C/D layout col = lane&15, row = (lane>>4)*4 + reg
    #pragma unroll
    for (int m = 0; m < 4; ++m) {
        const int row0 = m0 + wr * 64 + m * 16 + fg * 4;
        #pragma unroll
        for (int n = 0; n < 4; ++n) {
            const int col = n0 + wc * 64 + n * 16 + fr;
            const f32x4 v = acc[m][n];
            if (EP == 0) {
                float* C = (float*)C0 + coff;
                const float bv = BIAS ? bias[col] : 0.0f;
                #pragma unroll
                for (int i = 0; i < 4; ++i)
                    C[(long)(row0 + i) * ldc + col] = v[i] * scale + bv;
            } else if (EP == 1) {
                short* Chp = (short*)C0 + coff;
                short* Clp = (short*)C1 + coff;
                #pragma unroll
                for (int i = 0; i < 4; ++i) {
                    const float val = v[i] * scale;
                    const unsigned h = bf16_rne(val);
                    const long o = (long)(row0 + i) * ldc + col;
                    Chp[o] = (short)h;
                    Clp[o] = (short)bf16_rne(val - __uint_as_float(h << 16));
                }
            } else {  // EP == 2: transposed split write (V^T)
                short* Chp = (short*)C0 + coff;
                short* Clp = (short*)C1 + coff;
                short4 hv, lv;
                const float v0 = v[0] * scale, v1 = v[1] * scale,
                            v2 = v[2] * scale, v3 = v[3] * scale;
                unsigned h;
                h = bf16_rne(v0); hv.x = (short)h; lv.x = (short)bf16_rne(v0 - __uint_as_float(h << 16));
                h = bf16_rne(v1); hv.y = (short)h; lv.y = (short)bf16_rne(v1 - __uint_as_float(h << 16));
                h = bf16_rne(v2); hv.z = (short)h; lv.z = (short)bf16_rne(v2 - __uint_as_float(h << 16));
                h = bf16_rne(v3); hv.w = (short)h; lv.w = (short)bf16_rne(v3 - __uint_as_float(h << 16));
                const long o = (long)col * ldc + row0;
                *(short4*)&Chp[o] = hv;
                *(short4*)&Clp[o] = lv;
            }
        }
    }
}

// ---------------------------------------------------------------------------
// In-place softmax over rows of 1024. One 256-thread block per row.
__global__ __launch_bounds__(256) void softmax_rows(float* __restrict__ attn)
{
    const long row = blockIdx.x;
    float* p = attn + row * 1024 + (long)threadIdx.x * 4;
    float4 v = *reinterpret_cast<float4*>(p);

    float m = fmaxf(fmaxf(v.x, v.y), fmaxf(v.z, v.w));
    #pragma unroll
    for (int off = 32; off > 0; off >>= 1)
        m = fmaxf(m, __shfl_down(m, off));

    __shared__ float red[4];
    const int wave = threadIdx.x >> 6, lane = threadIdx.x & 63;
    if (lane == 0) red[wave] = m;
    __syncthreads();
    m = fmaxf(fmaxf(red[0], red[1]), fmaxf(red[2], red[3]));
    __syncthreads();

    v.x = __expf(v.x - m); v.y = __expf(v.y - m);
    v.z = __expf(v.z - m); v.w = __expf(v.w - m);
    float s = v.x + v.y + v.z + v.w;
    #pragma unroll
    for (int off = 32; off > 0; off >>= 1)
        s += __shfl_down(s, off);
    if (lane == 0) red[wave] = s;
    __syncthreads();
    s = red[0] + red[1] + red[2] + red[3];

    const float r = 1.0f / s;
    v.x *= r; v.y *= r; v.z *= r; v.w *= r;
    *reinterpret_cast<float4*>(p) = v;
}

// ---------------------------------------------------------------------------
extern "C" void kernel_launch(void* const* d_in, const int* in_sizes, int n_in,
                              void* d_out, int out_size, void* d_ws, size_t ws_size,
                              hipStream_t stream)
{
    const float* query  = (const float*)d_in[0];  // (8,1024,1024)
    const float* key    = (const float*)d_in[1];  // (8,1024,768)
    const float* value  = (const float*)d_in[2];  // (8,1024,768)
    const float* w_q    = (const float*)d_in[3];  // (8,1024,128)
    const float* w_k    = (const float*)d_in[4];  // (8,768,128)
    const float* w_v    = (const float*)d_in[5];  // (8,768,128)
    const float* proj_w = (const float*)d_in[6];  // (1024,1024)
    const float* proj_b = (const float*)d_in[7];  // (1024,)

    float* out  = (float*)d_out;
    float* attn = out + (size_t)8 * 1024 * 1024;   // [h][b][1024][1024] fp32

    // --- persistent split buffers in ws (100 MB total) ---
    short* ws   = (short*)d_ws;
    short* Qhi  = ws;                    // [h][b][l][128]
    short* Qlo  = Qhi + 8388608;
    short* Khi  = Qlo + 8388608;
    short* Klo  = Khi + 8388608;
    short* VThi = Klo + 8388608;         // [h][b][128][l]
    short* VTlo = VThi + 8388608;
    short* pwh  = VTlo + 8388608;        // [1024][1024]
    short* pwl  = pwh + 1048576;
    short* Ohi  = Qhi;                   // reuse Q region after QK^T
    short* Olo  = Qlo;

    // --- transient splits live in the (not yet written) attn region ---
    short* sc   = (short*)attn;
    short* wTqh = sc;                    // [h][128][1024]
    short* wTql = wTqh + 1048576;
    short* wTkh = wTql + 1048576;        // [h][128][768]
    short* wTkl = wTkh + 786432;
    short* wTvh = wTkl + 786432;
    short* wTvl = wTvh + 786432;
    short* qsh  = wTvl + 786432;         // query split [8][1024][1024]
    short* qsl  = qsh + 8388608;
    short* ksh  = qsl + 8388608;         // key split [8][1024][768]
    short* ksl  = ksh + 6291456;
    short* vsh  = ksl + 6291456;         // value split
    short* vsl  = vsh + 6291456;

    const dim3 blk(256);
    const float isq = 0.08838834764831845f;  // 1/sqrt(128), folded into Q

    // 0) one-time splits / transposed-split weights
    split_f32<<<4096, blk, 0, stream>>>(query, qsh, qsl);
    split_f32<<<3072, blk, 0, stream>>>(key, ksh, ksl);
    split_f32<<<3072, blk, 0, stream>>>(value, vsh, vsl);
    split_f32<<<512,  blk, 0, stream>>>(proj_w, pwh, pwl);
    transpose_split<<<dim3(4, 32, 8), blk, 0, stream>>>(w_q, wTqh, wTql, 1024, 128);
    transpose_split<<<dim3(4, 24, 8), blk, 0, stream>>>(w_k, wTkh, wTkl, 768, 128);
    transpose_split<<<dim3(4, 24, 8), blk, 0, stream>>>(w_v, wTvh, wTvl, 768, 128);

    // 1) Q = (query @ w_q) * isq -> split   [h][b][l][128]
    gemm_bb<false, 1, false><<<dim3(1, 8, 64), blk, 0, stream>>>(
        qsh, qsl, 1024, 0L, 1048576L,
        wTqh, wTql, 1024, 131072L, 0L,
        Qhi, Qlo, 128, 1048576L, 131072L,
        1024, isq, nullptr);

    // 2) K = key @ w_k -> split
    gemm_bb<false, 1, false><<<dim3(1, 8, 64), blk, 0, stream>>>(
        ksh, ksl, 768, 0L, 786432L,
        wTkh, wTkl, 768, 98304L, 0L,
        Khi, Klo, 128, 1048576L, 131072L,
        768, 1.0f, nullptr);

    // 3) V^T = (value @ w_v)^T -> split    [h][b][128][l]
    gemm_bb<false, 2, false><<<dim3(1, 8, 64), blk, 0, stream>>>(
        vsh, vsl, 768, 0L, 786432L,
        wTvh, wTvl, 768, 98304L, 0L,
        VThi, VTlo, 1024, 1048576L, 131072L,
        768, 1.0f, nullptr);

    // 4) S = Q K^T -> attn (fp32; scale already folded into Q)
    gemm_bb<false, 0, false><<<dim3(8, 8, 64), blk, 0, stream>>>(
        Qhi, Qlo, 128, 1048576L, 131072L,
        Khi, Klo, 128, 1048576L, 131072L,
        attn, nullptr, 1024, 8388608L, 1048576L,
        128, 1.0f, nullptr);

    // 5) softmax rows in place
    softmax_rows<<<65536, blk, 0, stream>>>(attn);

    // 6) O = attn @ V -> split, concat layout [b][l][h*128+d]
    gemm_bb<true, 1, false><<<dim3(1, 8, 64), blk, 0, stream>>>(
        attn, nullptr, 1024, 8388608L, 1048576L,
        VThi, VTlo, 1024, 1048576L, 131072L,
        Ohi, Olo, 1024, 128L, 1048576L,
        1024, 1.0f, nullptr);

    // 7) out = O @ proj_w^T + proj_b
    gemm_bb<false, 0, true><<<dim3(8, 64, 1), blk, 0, stream>>>(
        Ohi, Olo, 1024, 0L, 0L,
        pwh, pwl, 1024, 0L, 0L,
        out, nullptr, 1024, 0L, 0L,
        1024, 1.0f, proj_b);
}

// Round 6
// 830.648 us; speedup vs baseline: 1.0636x; 1.0064x over previous
//
#include <hip/hip_runtime.h>
#include <math.h>

// ---------------------------------------------------------------------------
// CrossAttention via pre-split bf16-pair MFMA GEMMs (fp32-class accuracy).
//   B=8, LQ=LKV=1024, EQ=1024, EKV=768, H=8, HD=128
//   d_out = [ out (8*1024*1024) | attn (64*1024*1024) ] fp32
//
// x carried as bf16 pairs (hi, lo), A.B = Ahi.Bhi + Ahi.Blo + Alo.Bhi.
// GEMM K-loop: double-buffered 2-phase pipeline with counted vmcnt waits
// (T3/T4 minimum recipe) — prefetch DMAs stay in flight across barriers;
// no vmcnt(0) drain in the main loop.
// ---------------------------------------------------------------------------

using bf16x8 = __attribute__((ext_vector_type(8))) short;
using f32x4  = __attribute__((ext_vector_type(4))) float;

__device__ __forceinline__ unsigned bf16_rne(float x) {
    unsigned u = __float_as_uint(x);
    return (u + 0x7fffu + ((u >> 16) & 1u)) >> 16;
}

#define AS1 __attribute__((address_space(1)))
#define AS3 __attribute__((address_space(3)))

__device__ __forceinline__ void gl_lds16(const short* g, short* l) {
    __builtin_amdgcn_global_load_lds((AS1 unsigned*)g, (AS3 unsigned*)l, 16, 0, 0);
}

// ---------------------------------------------------------------------------
__global__ __launch_bounds__(256) void split_f32(
    const float* __restrict__ src, short* __restrict__ hi,
    short* __restrict__ lo)
{
    const long i = ((long)blockIdx.x * 256 + threadIdx.x) * 8;
    const float4 a = *(const float4*)(src + i);
    const float4 b = *(const float4*)(src + i + 4);
    const float fv[8] = {a.x, a.y, a.z, a.w, b.x, b.y, b.z, b.w};
    bf16x8 h, l;
    #pragma unroll
    for (int j = 0; j < 8; ++j) {
        unsigned hb = bf16_rne(fv[j]);
        h[j] = (short)hb;
        l[j] = (short)bf16_rne(fv[j] - __uint_as_float(hb << 16));
    }
    *(bf16x8*)(hi + i) = h;
    *(bf16x8*)(lo + i) = l;
}

// ---------------------------------------------------------------------------
__global__ __launch_bounds__(256) void transpose_split(
    const float* __restrict__ src, short* __restrict__ dhi,
    short* __restrict__ dlo, int R, int C)
{
    __shared__ float tile[32][33];
    src += (long)blockIdx.z * R * C;
    dhi += (long)blockIdx.z * R * C;
    dlo += (long)blockIdx.z * R * C;
    const int r0 = blockIdx.y * 32, c0 = blockIdx.x * 32;
    const int tx = threadIdx.x & 31, ty = threadIdx.x >> 5;
    #pragma unroll
    for (int i = 0; i < 4; ++i)
        tile[ty + i * 8][tx] = src[(long)(r0 + ty + i * 8) * C + c0 + tx];
    __syncthreads();
    #pragma unroll
    for (int i = 0; i < 4; ++i) {
        const float v = tile[tx][ty + i * 8];
        const unsigned h = bf16_rne(v);
        const long o = (long)(c0 + ty + i * 8) * R + r0 + tx;
        dhi[o] = (short)h;
        dlo[o] = (short)bf16_rne(v - __uint_as_float(h << 16));
    }
}

// ---------------------------------------------------------------------------
// Split-3 bf16-pair GEMM, 128x128 tile, BK=32, 4 waves (2x2), 4x4 frags.
// Pipelined: dbuf LDS (64 KB), counted vmcnt, raw s_barrier (no drain).
template <bool AF32, int EP, bool BIAS>
__global__ __launch_bounds__(256, 2) void gemm_bb(
    const void* __restrict__ A0, const void* __restrict__ A1, int lda, long aHS, long aBS,
    const short* __restrict__ B0, const short* __restrict__ B1, int ldb, long bHS, long bBS,
    void* __restrict__ C0, void* __restrict__ C1, int ldc, long cHS, long cBS,
    int K, float scale, const float* __restrict__ bias)
{
    const int z = blockIdx.z, hh = z >> 3, bb = z & 7;
    const long aoff = (long)hh * aHS + (long)bb * aBS;
    const long boff = (long)hh * bHS + (long)bb * bBS;
    const long coff = (long)hh * cHS + (long)bb * cBS;

    // two static buffers per operand half (static indexing -> clean aliasing)
    __shared__ short lA0h[4096], lA0l[4096], lB0h[4096], lB0l[4096];
    __shared__ short lA1h[4096], lA1l[4096], lB1h[4096], lB1l[4096];

    const int t    = threadIdx.x;
    const int lane = t & 63, wid = t >> 6;
    const int wr = wid >> 1, wc = wid & 1;
    const int fr = lane & 15, fg = lane >> 4;

    const int m0 = blockIdx.y * 128, n0 = blockIdx.x * 128;

    const short* Bh = B0 + boff;
    const short* Bl = B1 + boff;
    const short* Ah = AF32 ? nullptr : (const short*)A0 + aoff;
    const short* Al = AF32 ? nullptr : (const short*)A1 + aoff;
    const float* Af = AF32 ? (const float*)A0 + aoff : nullptr;

    const int glrow = (lane >> 2);          // + wid*32 + j*16
    const int glk   = (lane & 3) * 8;
    const int srow  = t >> 1;               // AF32 on-fly split mapping
    const int shalf = (t & 1) * 16;

    f32x4 acc[4][4] = {};

    // ---- stage one K-tile (32 wide) into the given buffers ----
    auto stage = [&](short* dAh, short* dAl, short* dBh, short* dBl, int kk) {
        if (AF32) {
            // fp32 A loads issued FIRST, B DMA second: consuming A later
            // leaves B's DMAs (younger) in flight.
            const float* g = Af + (long)(m0 + srow) * lda + kk + shalf;
            const float4 f0 = *(const float4*)(g);
            const float4 f1 = *(const float4*)(g + 4);
            const float4 f2 = *(const float4*)(g + 8);
            const float4 f3 = *(const float4*)(g + 12);
            #pragma unroll
            for (int j = 0; j < 2; ++j) {
                const int rowb = wid * 32 + j * 16 + glrow;
                const long go = (long)(n0 + rowb) * ldb + kk + glk;
                gl_lds16(Bh + go, &dBh[(wid * 2 + j) * 512]);
                gl_lds16(Bl + go, &dBl[(wid * 2 + j) * 512]);
            }
            const float fv[16] = {f0.x, f0.y, f0.z, f0.w, f1.x, f1.y, f1.z, f1.w,
                                  f2.x, f2.y, f2.z, f2.w, f3.x, f3.y, f3.z, f3.w};
            bf16x8 h0, l0, h1, l1;
            #pragma unroll
            for (int i = 0; i < 8; ++i) {
                unsigned ha = bf16_rne(fv[i]);
                h0[i] = (short)ha;
                l0[i] = (short)bf16_rne(fv[i] - __uint_as_float(ha << 16));
                unsigned hb = bf16_rne(fv[8 + i]);
                h1[i] = (short)hb;
                l1[i] = (short)bf16_rne(fv[8 + i] - __uint_as_float(hb << 16));
            }
            const int sb = srow * 32 + shalf;
            *(bf16x8*)&dAh[sb] = h0;  *(bf16x8*)&dAh[sb + 8] = h1;
            *(bf16x8*)&dAl[sb] = l0;  *(bf16x8*)&dAl[sb + 8] = l1;
        } else {
            #pragma unroll
            for (int j = 0; j < 2; ++j) {
                const int rowb = wid * 32 + j * 16 + glrow;
                const long go = (long)(m0 + rowb) * lda + kk + glk;
                gl_lds16(Ah + go, &dAh[(wid * 2 + j) * 512]);
                gl_lds16(Al + go, &dAl[(wid * 2 + j) * 512]);
            }
            #pragma unroll
            for (int j = 0; j < 2; ++j) {
                const int rowb = wid * 32 + j * 16 + glrow;
                const long go = (long)(n0 + rowb) * ldb + kk + glk;
                gl_lds16(Bh + go, &dBh[(wid * 2 + j) * 512]);
                gl_lds16(Bl + go, &dBl[(wid * 2 + j) * 512]);
            }
        }
    };

    // ---- one K-tile of MFMAs from the given buffers ----
    auto compute = [&](const short* sAh, const short* sAl,
                       const short* sBh, const short* sBl) {
        bf16x8 va[4], wa[4];
        #pragma unroll
        for (int m = 0; m < 4; ++m) {
            const int off = (wr * 64 + m * 16 + fr) * 32 + fg * 8;
            va[m] = *(const bf16x8*)&sAh[off];
            wa[m] = *(const bf16x8*)&sAl[off];
        }
        __builtin_amdgcn_s_setprio(1);
        #pragma unroll
        for (int n = 0; n < 4; ++n) {
            const int off = (wc * 64 + n * 16 + fr) * 32 + fg * 8;
            const bf16x8 vb = *(const bf16x8*)&sBh[off];
            const bf16x8 wb = *(const bf16x8*)&sBl[off];
            #pragma unroll
            for (int m = 0; m < 4; ++m) {
                acc[m][n] = __builtin_amdgcn_mfma_f32_16x16x32_bf16(va[m], vb, acc[m][n], 0, 0, 0);
                acc[m][n] = __builtin_amdgcn_mfma_f32_16x16x32_bf16(va[m], wb, acc[m][n], 0, 0, 0);
                acc[m][n] = __builtin_amdgcn_mfma_f32_16x16x32_bf16(wa[m], vb, acc[m][n], 0, 0, 0);
            }
        }
        __builtin_amdgcn_s_setprio(0);
    };

    // ---- pipelined main loop (2 K-tiles per iteration, static buffers) ----
    stage(lA0h, lA0l, lB0h, lB0l, 0);
    for (int k0 = 0; k0 < K; k0 += 64) {
        // half 1: prefetch tile k0+32 into buf1, compute tile k0 from buf0
        stage(lA1h, lA1l, lB1h, lB1l, k0 + 32);
        if (AF32) asm volatile("s_waitcnt vmcnt(4)" ::: "memory");
        else      asm volatile("s_waitcnt vmcnt(8)" ::: "memory");
        __builtin_amdgcn_s_barrier();
        compute(lA0h, lA0l, lB0h, lB0l);
        asm volatile("s_waitcnt lgkmcnt(0)" ::: "memory");
        __builtin_amdgcn_s_barrier();

        // half 2: prefetch tile k0+64 into buf0, compute tile k0+32 from buf1
        if (k0 + 64 < K) {
            stage(lA0h, lA0l, lB0h, lB0l, k0 + 64);
            if (AF32) asm volatile("s_waitcnt vmcnt(4)" ::: "memory");
            else      asm volatile("s_waitcnt vmcnt(8)" ::: "memory");
        } else {
            asm volatile("s_waitcnt vmcnt(0)" ::: "memory");
        }
        __builtin_amdgcn_s_barrier();
        compute(lA1h, lA1l, lB1h, lB1l);
        asm volatile("s_waitcnt lgkmcnt(0)" ::: "memory");
        __builtin_amdgcn_s_barrier();
    }

    // ---- epilogue: C/D layout col = lane&15, row = (lane>>4)*4 + reg ----
    #pragma unroll
    for (int m = 0; m < 4; ++m) {
        const int row0 = m0 + wr * 64 + m * 16 + fg * 4;
        #pragma unroll
        for (int n = 0; n < 4; ++n) {
            const int col = n0 + wc * 64 + n * 16 + fr;
            const f32x4 v = acc[m][n];
            if (EP == 0) {
                float* C = (float*)C0 + coff;
                const float bv = BIAS ? bias[col] : 0.0f;
                #pragma unroll
                for (int i = 0; i < 4; ++i)
                    C[(long)(row0 + i) * ldc + col] = v[i] * scale + bv;
            } else if (EP == 1) {
                short* Chp = (short*)C0 + coff;
                short* Clp = (short*)C1 + coff;
                #pragma unroll
                for (int i = 0; i < 4; ++i) {
                    const float val = v[i] * scale;
                    const unsigned h = bf16_rne(val);
                    const long o = (long)(row0 + i) * ldc + col;
                    Chp[o] = (short)h;
                    Clp[o] = (short)bf16_rne(val - __uint_as_float(h << 16));
                }
            } else {  // EP == 2: transposed split write (V^T)
                short* Chp = (short*)C0 + coff;
                short* Clp = (short*)C1 + coff;
                short4 hv, lv;
                const float v0 = v[0] * scale, v1 = v[1] * scale,
                            v2 = v[2] * scale, v3 = v[3] * scale;
                unsigned h;
                h = bf16_rne(v0); hv.x = (short)h; lv.x = (short)bf16_rne(v0 - __uint_as_float(h << 16));
                h = bf16_rne(v1); hv.y = (short)h; lv.y = (short)bf16_rne(v1 - __uint_as_float(h << 16));
                h = bf16_rne(v2); hv.z = (short)h; lv.z = (short)bf16_rne(v2 - __uint_as_float(h << 16));
                h = bf16_rne(v3); hv.w = (short)h; lv.w = (short)bf16_rne(v3 - __uint_as_float(h << 16));
                const long o = (long)col * ldc + row0;
                *(short4*)&Chp[o] = hv;
                *(short4*)&Clp[o] = lv;
            }
        }
    }
}

// ---------------------------------------------------------------------------
__global__ __launch_bounds__(256) void softmax_rows(float* __restrict__ attn)
{
    const long row = blockIdx.x;
    float* p = attn + row * 1024 + (long)threadIdx.x * 4;
    float4 v = *reinterpret_cast<float4*>(p);

    float m = fmaxf(fmaxf(v.x, v.y), fmaxf(v.z, v.w));
    #pragma unroll
    for (int off = 32; off > 0; off >>= 1)
        m = fmaxf(m, __shfl_down(m, off));

    __shared__ float red[4];
    const int wave = threadIdx.x >> 6, lane = threadIdx.x & 63;
    if (lane == 0) red[wave] = m;
    __syncthreads();
    m = fmaxf(fmaxf(red[0], red[1]), fmaxf(red[2], red[3]));
    __syncthreads();

    v.x = __expf(v.x - m); v.y = __expf(v.y - m);
    v.z = __expf(v.z - m); v.w = __expf(v.w - m);
    float s = v.x + v.y + v.z + v.w;
    #pragma unroll
    for (int off = 32; off > 0; off >>= 1)
        s += __shfl_down(s, off);
    if (lane == 0) red[wave] = s;
    __syncthreads();
    s = red[0] + red[1] + red[2] + red[3];

    const float r = 1.0f / s;
    v.x *= r; v.y *= r; v.z *= r; v.w *= r;
    *reinterpret_cast<float4*>(p) = v;
}

// ---------------------------------------------------------------------------
extern "C" void kernel_launch(void* const* d_in, const int* in_sizes, int n_in,
                              void* d_out, int out_size, void* d_ws, size_t ws_size,
                              hipStream_t stream)
{
    const float* query  = (const float*)d_in[0];  // (8,1024,1024)
    const float* key    = (const float*)d_in[1];  // (8,1024,768)
    const float* value  = (const float*)d_in[2];  // (8,1024,768)
    const float* w_q    = (const float*)d_in[3];  // (8,1024,128)
    const float* w_k    = (const float*)d_in[4];  // (8,768,128)
    const float* w_v    = (const float*)d_in[5];  // (8,768,128)
    const float* proj_w = (const float*)d_in[6];  // (1024,1024)
    const float* proj_b = (const float*)d_in[7];  // (1024,)

    float* out  = (float*)d_out;
    float* attn = out + (size_t)8 * 1024 * 1024;   // [h][b][1024][1024] fp32

    // --- persistent split buffers in ws (100 MB total) ---
    short* ws   = (short*)d_ws;
    short* Qhi  = ws;                    // [h][b][l][128]
    short* Qlo  = Qhi + 8388608;
    short* Khi  = Qlo + 8388608;
    short* Klo  = Khi + 8388608;
    short* VThi = Klo + 8388608;         // [h][b][128][l]
    short* VTlo = VThi + 8388608;
    short* pwh  = VTlo + 8388608;        // [1024][1024]
    short* pwl  = pwh + 1048576;
    short* Ohi  = Qhi;                   // reuse Q region after QK^T
    short* Olo  = Qlo;

    // --- transient splits live in the (not yet written) attn region ---
    short* sc   = (short*)attn;
    short* wTqh = sc;                    // [h][128][1024]
    short* wTql = wTqh + 1048576;
    short* wTkh = wTql + 1048576;        // [h][128][768]
    short* wTkl = wTkh + 786432;
    short* wTvh = wTkl + 786432;
    short* wTvl = wTvh + 786432;
    short* qsh  = wTvl + 786432;         // query split [8][1024][1024]
    short* qsl  = qsh + 8388608;
    short* ksh  = qsl + 8388608;         // key split [8][1024][768]
    short* ksl  = ksh + 6291456;
    short* vsh  = ksl + 6291456;         // value split
    short* vsl  = vsh + 6291456;

    const dim3 blk(256);
    const float isq = 0.08838834764831845f;  // 1/sqrt(128), folded into Q

    // 0) one-time splits / transposed-split weights
    split_f32<<<4096, blk, 0, stream>>>(query, qsh, qsl);
    split_f32<<<3072, blk, 0, stream>>>(key, ksh, ksl);
    split_f32<<<3072, blk, 0, stream>>>(value, vsh, vsl);
    split_f32<<<512,  blk, 0, stream>>>(proj_w, pwh, pwl);
    transpose_split<<<dim3(4, 32, 8), blk, 0, stream>>>(w_q, wTqh, wTql, 1024, 128);
    transpose_split<<<dim3(4, 24, 8), blk, 0, stream>>>(w_k, wTkh, wTkl, 768, 128);
    transpose_split<<<dim3(4, 24, 8), blk, 0, stream>>>(w_v, wTvh, wTvl, 768, 128);

    // 1) Q = (query @ w_q) * isq -> split   [h][b][l][128]
    gemm_bb<false, 1, false><<<dim3(1, 8, 64), blk, 0, stream>>>(
        qsh, qsl, 1024, 0L, 1048576L,
        wTqh, wTql, 1024, 131072L, 0L,
        Qhi, Qlo, 128, 1048576L, 131072L,
        1024, isq, nullptr);

    // 2) K = key @ w_k -> split
    gemm_bb<false, 1, false><<<dim3(1, 8, 64), blk, 0, stream>>>(
        ksh, ksl, 768, 0L, 786432L,
        wTkh, wTkl, 768, 98304L, 0L,
        Khi, Klo, 128, 1048576L, 131072L,
        768, 1.0f, nullptr);

    // 3) V^T = (value @ w_v)^T -> split    [h][b][128][l]
    gemm_bb<false, 2, false><<<dim3(1, 8, 64), blk, 0, stream>>>(
        vsh, vsl, 768, 0L, 786432L,
        wTvh, wTvl, 768, 98304L, 0L,
        VThi, VTlo, 1024, 1048576L, 131072L,
        768, 1.0f, nullptr);

    // 4) S = Q K^T -> attn (fp32; scale already folded into Q)
    gemm_bb<false, 0, false><<<dim3(8, 8, 64), blk, 0, stream>>>(
        Qhi, Qlo, 128, 1048576L, 131072L,
        Khi, Klo, 128, 1048576L, 131072L,
        attn, nullptr, 1024, 8388608L, 1048576L,
        128, 1.0f, nullptr);

    // 5) softmax rows in place
    softmax_rows<<<65536, blk, 0, stream>>>(attn);

    // 6) O = attn @ V -> split, concat layout [b][l][h*128+d]
    gemm_bb<true, 1, false><<<dim3(1, 8, 64), blk, 0, stream>>>(
        attn, nullptr, 1024, 8388608L, 1048576L,
        VThi, VTlo, 1024, 1048576L, 131072L,
        Ohi, Olo, 1024, 128L, 1048576L,
        1024, 1.0f, nullptr);

    // 7) out = O @ proj_w^T + proj_b
    gemm_bb<false, 0, true><<<dim3(8, 64, 1), blk, 0, stream>>>(
        Ohi, Olo, 1024, 0L, 0L,
        pwh, pwl, 1024, 0L, 0L,
        out, nullptr, 1024, 0L, 0L,
        1024, 1.0f, proj_b);
}